// Round 2
// baseline (1787.466 us; speedup 1.0000x reference)
//
#include <hip/hip_runtime.h>
#include <math.h>

#define BB 2
#define LL 2048
#define DMODEL 256
#define NH 8
#define DHEAD 32
#define LL2 (LL*LL)            // 4,194,304 floats per (b,h) attn slab
#define NQ (BB*NH*LL*DHEAD)    // 1,048,576 floats per Q/K/V/ctx tensor

constexpr float SCALE_INV = 0.17677669529663687f;  // 1/sqrt(32)

// ---------------- Kernel 1: QKV projections ----------------
// C[row][col] = sum_k X[row][k] * W[col][k]; stored as O[b][h][l][d].
// For z<=1 (Q,K) also duplicate the (b=1,h=7) slice into ws (dup) so the
// late attn15 kernel can read it after the tail scratch is overwritten.
__global__ __launch_bounds__(256) void proj_kernel(
    const float* __restrict__ xq, const float* __restrict__ xk, const float* __restrict__ xv,
    const float* __restrict__ Wq, const float* __restrict__ Wk, const float* __restrict__ Wv,
    float* __restrict__ Qo, float* __restrict__ Ko, float* __restrict__ Vo,
    float* __restrict__ Q15, float* __restrict__ K15)
{
    const float* X; const float* W; float* O; float* dup;
    if (blockIdx.z == 0)      { X = xq; W = Wq; O = Qo; dup = Q15; }
    else if (blockIdx.z == 1) { X = xk; W = Wk; O = Ko; dup = K15; }
    else                      { X = xv; W = Wv; O = Vo; dup = nullptr; }

    __shared__ float Xs[64][33];
    __shared__ float Ws[64][33];

    const int t  = threadIdx.x;
    const int m0 = blockIdx.x * 64;
    const int n0 = blockIdx.y * 64;
    const int ty = t >> 4;
    const int tx = t & 15;

    float acc[4][4] = {};

    for (int k0 = 0; k0 < DMODEL; k0 += 32) {
#pragma unroll
        for (int r = 0; r < 2; ++r) {
            int f   = t + 256 * r;          // 0..511
            int row = f >> 3;
            int c   = (f & 7) << 2;
            float4 xv4 = *(const float4*)(X + (size_t)(m0 + row) * DMODEL + k0 + c);
            Xs[row][c+0] = xv4.x; Xs[row][c+1] = xv4.y; Xs[row][c+2] = xv4.z; Xs[row][c+3] = xv4.w;
            float4 wv4 = *(const float4*)(W + (size_t)(n0 + row) * DMODEL + k0 + c);
            Ws[row][c+0] = wv4.x; Ws[row][c+1] = wv4.y; Ws[row][c+2] = wv4.z; Ws[row][c+3] = wv4.w;
        }
        __syncthreads();
#pragma unroll
        for (int kk = 0; kk < 32; ++kk) {
            float a[4], bv[4];
#pragma unroll
            for (int i = 0; i < 4; ++i) a[i]  = Xs[ty*4+i][kk];
#pragma unroll
            for (int j = 0; j < 4; ++j) bv[j] = Ws[tx*4+j][kk];
#pragma unroll
            for (int i = 0; i < 4; ++i)
#pragma unroll
                for (int j = 0; j < 4; ++j)
                    acc[i][j] = fmaf(a[i], bv[j], acc[i][j]);
        }
        __syncthreads();
    }

#pragma unroll
    for (int i = 0; i < 4; ++i) {
        int row = m0 + ty*4 + i;
        int b   = row / LL;
        int l   = row % LL;
#pragma unroll
        for (int j = 0; j < 4; ++j) {
            int col = n0 + tx*4 + j;
            int h   = col >> 5;
            int d   = col & 31;
            O[(size_t)(((b*NH + h)*LL) + l) * DHEAD + d] = acc[i][j];
            if (dup && row >= LL && col >= 224) {
                dup[(size_t)(row - LL) * DHEAD + (col - 224)] = acc[i][j];
            }
        }
    }
}

// ---------------- Kernel 2: fused attention ----------------
// One block per (b,h, 32-row q tile). Two passes over k (recompute scheme):
//   A: online (max,sum) per q row (wave-local, shuffle-reduced)
//   B: recompute logits, write normalized attn (bh<15 only), accumulate PV.
// bh==15 blocks skip the attn store (their slab hosts the Q/K/V/ctx scratch)
// and instead record per-row (M, 1/S) in ws for the late attn15 kernel.
__global__ __launch_bounds__(256) void attn_kernel(
    const float* __restrict__ Q, const float* __restrict__ K, const float* __restrict__ V,
    const int* __restrict__ mask, const float* __restrict__ adj, const float* __restrict__ dist,
    const float* __restrict__ wA, const float* __restrict__ wD,
    float* __restrict__ attn, float* __restrict__ ctx,
    float* __restrict__ Mw, float* __restrict__ Sw)
{
    const int t    = threadIdx.x;
    const int bh   = blockIdx.y;          // b*NH + h
    const int b    = bh >> 3;
    const int h    = bh & 7;
    const int q0   = blockIdx.x * 32;
    const int kcol = t & 63;              // lane within wave
    const int wid  = t >> 6;              // wave id 0..3

    __shared__ float Qs[32][36];
    __shared__ float Ks[128][36];
    __shared__ float Vs[128][36];
    __shared__ float As[32][132];

    const float wa = wA[h];
    const float wd = wD[h];

    // load Q tile (32 x 32)
    {
        int row = t >> 3;
        int c   = (t & 7) << 2;
        float4 qv = *(const float4*)(Q + (size_t)(bh * LL + q0 + row) * DHEAD + c);
        Qs[row][c+0] = qv.x; Qs[row][c+1] = qv.y; Qs[row][c+2] = qv.z; Qs[row][c+3] = qv.w;
    }

    float M[8], S[8];
#pragma unroll
    for (int j = 0; j < 8; ++j) { M[j] = -INFINITY; S[j] = 0.0f; }

    const size_t kv_base = (size_t)bh * LL * DHEAD;

    // ---- Phase A: row stats ----
    for (int kt = 0; kt < 16; ++kt) {
#pragma unroll
        for (int r = 0; r < 4; ++r) {
            int f   = t + 256 * r;
            int row = f >> 3;
            int c   = (f & 7) << 2;
            float4 kv = *(const float4*)(K + kv_base + (size_t)(kt*128 + row) * DHEAD + c);
            Ks[row][c+0]=kv.x; Ks[row][c+1]=kv.y; Ks[row][c+2]=kv.z; Ks[row][c+3]=kv.w;
        }
        __syncthreads();

        float4 k0[8], k1[8];
        {
            const float4* p0 = (const float4*)&Ks[kcol][0];
            const float4* p1 = (const float4*)&Ks[kcol + 64][0];
#pragma unroll
            for (int c = 0; c < 8; ++c) { k0[c] = p0[c]; k1[c] = p1[c]; }
        }

        const int kg0 = kt*128 + kcol;
#pragma unroll
        for (int j = 0; j < 8; ++j) {
            int qq = wid + 4*j;
            float s0 = 0.f, s1 = 0.f;
            const float4* qp = (const float4*)&Qs[qq][0];
#pragma unroll
            for (int c = 0; c < 8; ++c) {
                float4 q4 = qp[c];
                s0 += q4.x*k0[c].x + q4.y*k0[c].y + q4.z*k0[c].z + q4.w*k0[c].w;
                s1 += q4.x*k1[c].x + q4.y*k1[c].y + q4.z*k1[c].z + q4.w*k1[c].w;
            }
            int qg = q0 + qq;
            size_t mi0 = (size_t)(b * LL + qg) * LL + kg0;
            size_t mi1 = mi0 + 64;
            float sm0 = (mask[mi0] == 1) ? s0 : 0.0f;
            float sm1 = (mask[mi1] == 1) ? s1 : 0.0f;
            float l0 = sm0 * (1.0f + adj[mi0]*wa + dist[mi0]*wd) * SCALE_INV;
            float l1 = sm1 * (1.0f + adj[mi1]*wa + dist[mi1]*wd) * SCALE_INV;
            float mn = fmaxf(M[j], fmaxf(l0, l1));
            S[j] = S[j]*__expf(M[j]-mn) + __expf(l0-mn) + __expf(l1-mn);
            M[j] = mn;
        }
        __syncthreads();
    }

    // wave-level (max,sum) reduction; each wave owns rows q ≡ wid (mod 4)
#pragma unroll
    for (int j = 0; j < 8; ++j) {
        float m = M[j], s = S[j];
#pragma unroll
        for (int off = 1; off < 64; off <<= 1) {
            float mo = __shfl_xor(m, off, 64);
            float so = __shfl_xor(s, off, 64);
            float mn = fmaxf(m, mo);
            s = s*__expf(m - mn) + so*__expf(mo - mn);
            m = mn;
        }
        M[j] = m;
        S[j] = 1.0f / s;    // store inverse sum
    }

    // bh==15: record stats for the late attn15 kernel
    if (bh == 15 && kcol == 0) {
#pragma unroll
        for (int j = 0; j < 8; ++j) {
            int qg = q0 + wid + 4*j;
            Mw[qg] = M[j];
            Sw[qg] = S[j];
        }
    }

    // ---- Phase B: recompute, write attn (bh<15), accumulate PV ----
    float acc[4] = {0.f, 0.f, 0.f, 0.f};
    const int dcol = t & 31;
    const int grp  = t >> 5;              // 0..7

    for (int kt = 0; kt < 16; ++kt) {
#pragma unroll
        for (int r = 0; r < 4; ++r) {
            int f   = t + 256 * r;
            int row = f >> 3;
            int c   = (f & 7) << 2;
            float4 kv = *(const float4*)(K + kv_base + (size_t)(kt*128 + row) * DHEAD + c);
            Ks[row][c+0]=kv.x; Ks[row][c+1]=kv.y; Ks[row][c+2]=kv.z; Ks[row][c+3]=kv.w;
            float4 vv = *(const float4*)(V + kv_base + (size_t)(kt*128 + row) * DHEAD + c);
            Vs[row][c+0]=vv.x; Vs[row][c+1]=vv.y; Vs[row][c+2]=vv.z; Vs[row][c+3]=vv.w;
        }
        __syncthreads();

        float4 k0[8], k1[8];
        {
            const float4* p0 = (const float4*)&Ks[kcol][0];
            const float4* p1 = (const float4*)&Ks[kcol + 64][0];
#pragma unroll
            for (int c = 0; c < 8; ++c) { k0[c] = p0[c]; k1[c] = p1[c]; }
        }

        const int kg0 = kt*128 + kcol;
#pragma unroll
        for (int j = 0; j < 8; ++j) {
            int qq = wid + 4*j;
            float s0 = 0.f, s1 = 0.f;
            const float4* qp = (const float4*)&Qs[qq][0];
#pragma unroll
            for (int c = 0; c < 8; ++c) {
                float4 q4 = qp[c];
                s0 += q4.x*k0[c].x + q4.y*k0[c].y + q4.z*k0[c].z + q4.w*k0[c].w;
                s1 += q4.x*k1[c].x + q4.y*k1[c].y + q4.z*k1[c].z + q4.w*k1[c].w;
            }
            int qg = q0 + qq;
            size_t mi0 = (size_t)(b * LL + qg) * LL + kg0;
            size_t mi1 = mi0 + 64;
            float sm0 = (mask[mi0] == 1) ? s0 : 0.0f;
            float sm1 = (mask[mi1] == 1) ? s1 : 0.0f;
            float l0 = sm0 * (1.0f + adj[mi0]*wa + dist[mi0]*wd) * SCALE_INV;
            float l1 = sm1 * (1.0f + adj[mi1]*wa + dist[mi1]*wd) * SCALE_INV;
            float p0 = __expf(l0 - M[j]) * S[j];
            float p1 = __expf(l1 - M[j]) * S[j];
            As[qq][kcol]      = p0;
            As[qq][kcol + 64] = p1;
            if (bh != 15) {
                size_t ai = (size_t)(bh * LL + qg) * LL + kg0;
                attn[ai]      = p0;
                attn[ai + 64] = p1;
            }
        }
        __syncthreads();

        // PV: thread owns (d = dcol) for 4 q rows (grp*4 .. grp*4+3), all 128 k
#pragma unroll
        for (int c = 0; c < 32; ++c) {
            int kl = c * 4;
            float v0 = Vs[kl+0][dcol];
            float v1 = Vs[kl+1][dcol];
            float v2 = Vs[kl+2][dcol];
            float v3 = Vs[kl+3][dcol];
#pragma unroll
            for (int jj = 0; jj < 4; ++jj) {
                int qq = grp * 4 + jj;
                float4 a4 = *(const float4*)&As[qq][kl];
                acc[jj] += a4.x*v0 + a4.y*v1 + a4.z*v2 + a4.w*v3;
            }
        }
        __syncthreads();
    }

#pragma unroll
    for (int jj = 0; jj < 4; ++jj) {
        int qg = q0 + grp*4 + jj;
        ctx[(size_t)(bh * LL + qg) * DHEAD + dcol] = acc[jj];
    }
}

// ---------------- Kernel 3: output projection ----------------
__global__ __launch_bounds__(256) void out_gemm_kernel(
    const float* __restrict__ ctx, const float* __restrict__ Wo, float* __restrict__ Y)
{
    __shared__ float Xs[64][33];
    __shared__ float Ws[64][33];

    const int t  = threadIdx.x;
    const int m0 = blockIdx.x * 64;
    const int n0 = blockIdx.y * 64;
    const int ty = t >> 4;
    const int tx = t & 15;

    float acc[4][4] = {};

    for (int kt = 0; kt < 8; ++kt) {      // k0 = kt*32, h = kt
#pragma unroll
        for (int r = 0; r < 2; ++r) {
            int f   = t + 256*r;
            int row = f >> 3;
            int c   = (f & 7) << 2;
            int grow = m0 + row;
            int b = grow / LL, l = grow % LL;
            float4 xv4 = *(const float4*)(ctx + (size_t)((b*NH + kt)*LL + l) * DHEAD + c);
            Xs[row][c+0]=xv4.x; Xs[row][c+1]=xv4.y; Xs[row][c+2]=xv4.z; Xs[row][c+3]=xv4.w;
            float4 wv4 = *(const float4*)(Wo + (size_t)(n0 + row) * DMODEL + kt*32 + c);
            Ws[row][c+0]=wv4.x; Ws[row][c+1]=wv4.y; Ws[row][c+2]=wv4.z; Ws[row][c+3]=wv4.w;
        }
        __syncthreads();
#pragma unroll
        for (int kk = 0; kk < 32; ++kk) {
            float a[4], bv[4];
#pragma unroll
            for (int i = 0; i < 4; ++i) a[i]  = Xs[ty*4+i][kk];
#pragma unroll
            for (int j = 0; j < 4; ++j) bv[j] = Ws[tx*4+j][kk];
#pragma unroll
            for (int i = 0; i < 4; ++i)
#pragma unroll
                for (int j = 0; j < 4; ++j)
                    acc[i][j] = fmaf(a[i], bv[j], acc[i][j]);
        }
        __syncthreads();
    }

#pragma unroll
    for (int i = 0; i < 4; ++i) {
        int row = m0 + ty*4 + i;
#pragma unroll
        for (int j = 0; j < 4; ++j) {
            int col = n0 + tx*4 + j;
            Y[(size_t)row * DMODEL + col] = acc[i][j];
        }
    }
}

// ---------------- Kernel 4: attn writes for bh==15 ----------------
// Recomputes logits from the ws Q/K copies (the tail scratch is being
// overwritten by this very kernel) and writes normalized attn[15].
__global__ __launch_bounds__(256) void attn15_kernel(
    const float* __restrict__ Q15, const float* __restrict__ K15,
    const int* __restrict__ mask, const float* __restrict__ adj, const float* __restrict__ dist,
    const float* __restrict__ wA, const float* __restrict__ wD,
    const float* __restrict__ Mw, const float* __restrict__ Sw,
    float* __restrict__ attn15)
{
    const int t    = threadIdx.x;
    const int q0   = blockIdx.x * 32;
    const int kcol = t & 63;
    const int wid  = t >> 6;

    __shared__ float Qs[32][36];
    __shared__ float Ks[128][36];

    const float wa = wA[7];
    const float wd = wD[7];

    {
        int row = t >> 3;
        int c   = (t & 7) << 2;
        float4 qv = *(const float4*)(Q15 + (size_t)(q0 + row) * DHEAD + c);
        Qs[row][c+0] = qv.x; Qs[row][c+1] = qv.y; Qs[row][c+2] = qv.z; Qs[row][c+3] = qv.w;
    }

    float Mr[8], Sr[8];
#pragma unroll
    for (int j = 0; j < 8; ++j) {
        int qg = q0 + wid + 4*j;
        Mr[j] = Mw[qg];
        Sr[j] = Sw[qg];
    }

    for (int kt = 0; kt < 16; ++kt) {
#pragma unroll
        for (int r = 0; r < 4; ++r) {
            int f   = t + 256 * r;
            int row = f >> 3;
            int c   = (f & 7) << 2;
            float4 kv = *(const float4*)(K15 + (size_t)(kt*128 + row) * DHEAD + c);
            Ks[row][c+0]=kv.x; Ks[row][c+1]=kv.y; Ks[row][c+2]=kv.z; Ks[row][c+3]=kv.w;
        }
        __syncthreads();

        float4 k0[8], k1[8];
        {
            const float4* p0 = (const float4*)&Ks[kcol][0];
            const float4* p1 = (const float4*)&Ks[kcol + 64][0];
#pragma unroll
            for (int c = 0; c < 8; ++c) { k0[c] = p0[c]; k1[c] = p1[c]; }
        }

        const int kg0 = kt*128 + kcol;
#pragma unroll
        for (int j = 0; j < 8; ++j) {
            int qq = wid + 4*j;
            float s0 = 0.f, s1 = 0.f;
            const float4* qp = (const float4*)&Qs[qq][0];
#pragma unroll
            for (int c = 0; c < 8; ++c) {
                float4 q4 = qp[c];
                s0 += q4.x*k0[c].x + q4.y*k0[c].y + q4.z*k0[c].z + q4.w*k0[c].w;
                s1 += q4.x*k1[c].x + q4.y*k1[c].y + q4.z*k1[c].z + q4.w*k1[c].w;
            }
            int qg = q0 + qq;
            size_t mi0 = (size_t)(LL + qg) * LL + kg0;      // b = 1
            size_t mi1 = mi0 + 64;
            float sm0 = (mask[mi0] == 1) ? s0 : 0.0f;
            float sm1 = (mask[mi1] == 1) ? s1 : 0.0f;
            float l0 = sm0 * (1.0f + adj[mi0]*wa + dist[mi0]*wd) * SCALE_INV;
            float l1 = sm1 * (1.0f + adj[mi1]*wa + dist[mi1]*wd) * SCALE_INV;
            size_t ai = (size_t)qg * LL + kg0;
            attn15[ai]      = __expf(l0 - Mr[j]) * Sr[j];
            attn15[ai + 64] = __expf(l1 - Mr[j]) * Sr[j];
        }
        __syncthreads();
    }
}

extern "C" void kernel_launch(void* const* d_in, const int* in_sizes, int n_in,
                              void* d_out, int out_size, void* d_ws, size_t ws_size,
                              hipStream_t stream)
{
    const float* q    = (const float*)d_in[0];
    const float* k    = (const float*)d_in[1];
    const float* v    = (const float*)d_in[2];
    const int*   mask = (const int*)d_in[3];
    const float* adj  = (const float*)d_in[4];
    const float* dist = (const float*)d_in[5];
    const float* Wq   = (const float*)d_in[6];
    const float* Wk   = (const float*)d_in[7];
    const float* Wv   = (const float*)d_in[8];
    const float* Wo   = (const float*)d_in[9];
    const float* wA   = (const float*)d_in[10];
    const float* wD   = (const float*)d_in[11];

    float* out  = (float*)d_out;                       // B*L*DM
    float* attn = out + (size_t)BB*LL*DMODEL;          // B*H*L*L

    // Scratch parked in attn[bh=15]'s slab (exactly 4*NQ floats = 16 MB).
    // It is fully dead before attn15_kernel overwrites it with real attn.
    float* tail = attn + (size_t)15 * LL2;
    float* Qw = tail;
    float* Kw = tail + (size_t)NQ;
    float* Vw = tail + (size_t)2 * NQ;
    float* Cw = tail + (size_t)3 * NQ;

    // Tiny ws: bh=15 Q/K slices + softmax stats (528 KB total).
    float* Q15 = (float*)d_ws;                 // 65536
    float* K15 = Q15 + (size_t)LL * DHEAD;     // 65536
    float* Mw  = K15 + (size_t)LL * DHEAD;     // 2048
    float* Sw  = Mw + LL;                      // 2048

    dim3 g1(64, 4, 3);
    proj_kernel<<<g1, 256, 0, stream>>>(q, k, v, Wq, Wk, Wv, Qw, Kw, Vw, Q15, K15);

    dim3 g2(LL/32, BB*NH);
    attn_kernel<<<g2, 256, 0, stream>>>(Qw, Kw, Vw, mask, adj, dist, wA, wD, attn, Cw, Mw, Sw);

    dim3 g3(64, 4);
    out_gemm_kernel<<<g3, 256, 0, stream>>>(Cw, Wo, out);

    attn15_kernel<<<LL/32, 256, 0, stream>>>(Q15, K15, mask, adj, dist, wA, wD, Mw, Sw,
                                             attn + (size_t)15 * LL2);
}

// Round 3
// 1700.708 us; speedup vs baseline: 1.0510x; 1.0510x over previous
//
#include <hip/hip_runtime.h>
#include <math.h>

#define BB 2
#define LL 2048
#define DMODEL 256
#define NH 8
#define DHEAD 32
#define LL2 (LL*LL)            // 4,194,304 floats per (b,h) attn slab
#define NQ (BB*NH*LL*DHEAD)    // 1,048,576 floats per Q/K/V/ctx tensor

constexpr float SCALE_INV = 0.17677669529663687f;  // 1/sqrt(32)

// ---------------- Kernel 1: QKV projections ----------------
__global__ __launch_bounds__(256) void proj_kernel(
    const float* __restrict__ xq, const float* __restrict__ xk, const float* __restrict__ xv,
    const float* __restrict__ Wq, const float* __restrict__ Wk, const float* __restrict__ Wv,
    float* __restrict__ Qo, float* __restrict__ Ko, float* __restrict__ Vo,
    float* __restrict__ Q15, float* __restrict__ K15)
{
    const float* X; const float* W; float* O; float* dup;
    if (blockIdx.z == 0)      { X = xq; W = Wq; O = Qo; dup = Q15; }
    else if (blockIdx.z == 1) { X = xk; W = Wk; O = Ko; dup = K15; }
    else                      { X = xv; W = Wv; O = Vo; dup = nullptr; }

    __shared__ float Xs[64][33];
    __shared__ float Ws[64][33];

    const int t  = threadIdx.x;
    const int m0 = blockIdx.x * 64;
    const int n0 = blockIdx.y * 64;
    const int ty = t >> 4;
    const int tx = t & 15;

    float acc[4][4] = {};

    for (int k0 = 0; k0 < DMODEL; k0 += 32) {
#pragma unroll
        for (int r = 0; r < 2; ++r) {
            int f   = t + 256 * r;
            int row = f >> 3;
            int c   = (f & 7) << 2;
            float4 xv4 = *(const float4*)(X + (size_t)(m0 + row) * DMODEL + k0 + c);
            Xs[row][c+0] = xv4.x; Xs[row][c+1] = xv4.y; Xs[row][c+2] = xv4.z; Xs[row][c+3] = xv4.w;
            float4 wv4 = *(const float4*)(W + (size_t)(n0 + row) * DMODEL + k0 + c);
            Ws[row][c+0] = wv4.x; Ws[row][c+1] = wv4.y; Ws[row][c+2] = wv4.z; Ws[row][c+3] = wv4.w;
        }
        __syncthreads();
#pragma unroll
        for (int kk = 0; kk < 32; ++kk) {
            float a[4], bv[4];
#pragma unroll
            for (int i = 0; i < 4; ++i) a[i]  = Xs[ty*4+i][kk];
#pragma unroll
            for (int j = 0; j < 4; ++j) bv[j] = Ws[tx*4+j][kk];
#pragma unroll
            for (int i = 0; i < 4; ++i)
#pragma unroll
                for (int j = 0; j < 4; ++j)
                    acc[i][j] = fmaf(a[i], bv[j], acc[i][j]);
        }
        __syncthreads();
    }

#pragma unroll
    for (int i = 0; i < 4; ++i) {
        int row = m0 + ty*4 + i;
        int b   = row / LL;
        int l   = row % LL;
#pragma unroll
        for (int j = 0; j < 4; ++j) {
            int col = n0 + tx*4 + j;
            int h   = col >> 5;
            int d   = col & 31;
            O[(size_t)(((b*NH + h)*LL) + l) * DHEAD + d] = acc[i][j];
            if (dup && row >= LL && col >= 224) {
                dup[(size_t)(row - LL) * DHEAD + (col - 224)] = acc[i][j];
            }
        }
    }
}

// ---------------- Kernel 2: single-pass flash attention ----------------
// One block per (b,h, 32-row q tile); 32 k-tiles of 64.
// Writes p' = exp(l - M_loc(tile)) to attn (bh<15), online (m,s,acc) flash
// update, correction factors cf = exp(M_loc - M_fin)/S to cfg (the `out`
// region, dead until out_gemm). bh==15 records final (M, 1/S) in ws.
__global__ __launch_bounds__(256, 4) void attn_main_kernel(
    const float* __restrict__ Q, const float* __restrict__ K, const float* __restrict__ V,
    const int* __restrict__ mask, const float* __restrict__ adj, const float* __restrict__ dist,
    const float* __restrict__ wA, const float* __restrict__ wD,
    float* __restrict__ attn, float* __restrict__ ctx, float* __restrict__ cfg,
    float* __restrict__ Mw, float* __restrict__ Sw)
{
    const int t    = threadIdx.x;
    const int bh   = blockIdx.y;
    const int b    = bh >> 3;
    const int h    = bh & 7;
    const int q0   = blockIdx.x * 32;
    const int kcol = t & 63;
    const int wid  = t >> 6;
    const int dcol = t & 31;
    const int grp  = t >> 5;

    __shared__ float Qs[32][36];
    __shared__ float Ks[64][36];
    __shared__ float Vs[64][36];
    __shared__ float As[32][68];   // cols 0..63 = p'; 64 = alpha; 65 = beta; 66 = invS
    __shared__ float Msh[32][33];  // per-(row,tile) local max

    const float wa = wA[h];
    const float wd = wD[h];

    {   // Q tile 32x32
        int row = t >> 3;
        int c   = (t & 7) << 2;
        float4 qv = *(const float4*)(Q + (size_t)(bh * LL + q0 + row) * DHEAD + c);
        Qs[row][c+0] = qv.x; Qs[row][c+1] = qv.y; Qs[row][c+2] = qv.z; Qs[row][c+3] = qv.w;
    }

    float m[8], s[8];
#pragma unroll
    for (int j = 0; j < 8; ++j) { m[j] = -INFINITY; s[j] = 0.0f; }
    float acc[4] = {0.f, 0.f, 0.f, 0.f};

    const size_t kv_base = (size_t)bh * LL * DHEAD;

    for (int kt = 0; kt < 32; ++kt) {
        // stage K,V tile (64 x 32)
#pragma unroll
        for (int r = 0; r < 2; ++r) {
            int f   = t + 256 * r;
            int row = f >> 3;
            int c   = (f & 7) << 2;
            float4 kv = *(const float4*)(K + kv_base + (size_t)(kt*64 + row) * DHEAD + c);
            Ks[row][c+0]=kv.x; Ks[row][c+1]=kv.y; Ks[row][c+2]=kv.z; Ks[row][c+3]=kv.w;
            float4 vv = *(const float4*)(V + kv_base + (size_t)(kt*64 + row) * DHEAD + c);
            Vs[row][c+0]=vv.x; Vs[row][c+1]=vv.y; Vs[row][c+2]=vv.z; Vs[row][c+3]=vv.w;
        }
        __syncthreads();

        float4 kf[8];
        {
            const float4* kp = (const float4*)&Ks[kcol][0];
#pragma unroll
            for (int c = 0; c < 8; ++c) kf[c] = kp[c];
        }

        const int kg = kt*64 + kcol;
#pragma unroll
        for (int j = 0; j < 8; ++j) {
            int qq = wid + 4*j;
            float s0 = 0.f;
            const float4* qp = (const float4*)&Qs[qq][0];
#pragma unroll
            for (int c = 0; c < 8; ++c) {
                float4 q4 = qp[c];
                s0 += q4.x*kf[c].x + q4.y*kf[c].y + q4.z*kf[c].z + q4.w*kf[c].w;
            }
            int qg = q0 + qq;
            size_t mi = (size_t)(b * LL + qg) * LL + kg;
            float sm = (mask[mi] == 1) ? s0 : 0.0f;
            float l  = sm * (1.0f + adj[mi]*wa + dist[mi]*wd) * SCALE_INV;

            // tile-local max (64-lane butterfly)
            float mloc = l;
#pragma unroll
            for (int off = 1; off < 64; off <<= 1)
                mloc = fmaxf(mloc, __shfl_xor(mloc, off, 64));

            float p = __expf(l - mloc);
            if (bh != 15) attn[(size_t)(bh * LL + qg) * LL + kg] = p;
            As[qq][kcol] = p;

            float ss = p;
#pragma unroll
            for (int off = 1; off < 64; off <<= 1)
                ss += __shfl_xor(ss, off, 64);

            float mnew  = fmaxf(m[j], mloc);
            float alpha = __expf(m[j] - mnew);
            float beta  = __expf(mloc - mnew);
            s[j] = s[j]*alpha + ss*beta;
            m[j] = mnew;
            if (kcol == 0) {
                Msh[qq][kt] = mloc;
                As[qq][64] = alpha;
                As[qq][65] = beta;
            }
        }
        __syncthreads();

        // PV: thread (grp,dcol) accumulates rows grp*4..+3, d = dcol
        float sum[4] = {0.f, 0.f, 0.f, 0.f};
#pragma unroll
        for (int c = 0; c < 16; ++c) {
            int kl = c * 4;
            float v0 = Vs[kl+0][dcol];
            float v1 = Vs[kl+1][dcol];
            float v2 = Vs[kl+2][dcol];
            float v3 = Vs[kl+3][dcol];
#pragma unroll
            for (int jj = 0; jj < 4; ++jj) {
                float4 a4 = *(const float4*)&As[grp*4+jj][kl];
                sum[jj] += a4.x*v0 + a4.y*v1 + a4.z*v2 + a4.w*v3;
            }
        }
#pragma unroll
        for (int jj = 0; jj < 4; ++jj) {
            int r = grp*4 + jj;
            acc[jj] = acc[jj]*As[r][64] + As[r][65]*sum[jj];
        }
        __syncthreads();
    }

    // epilogue: invS, cf, bh==15 stats
#pragma unroll
    for (int j = 0; j < 8; ++j) {
        int qq = wid + 4*j;
        int qg = q0 + qq;
        float inv = 1.0f / s[j];
        if (kcol == 0) As[qq][66] = inv;
        if (bh == 15 && kcol == 0) { Mw[qg] = m[j]; Sw[qg] = inv; }
        if (kcol < 32) {
            float cf = __expf(Msh[qq][kcol] - m[j]) * inv;
            cfg[((size_t)(bh * LL + qg)) * 32 + kcol] = cf;
        }
    }
    __syncthreads();

#pragma unroll
    for (int jj = 0; jj < 4; ++jj) {
        int r  = grp*4 + jj;
        int qg = q0 + r;
        ctx[(size_t)(bh * LL + qg) * DHEAD + dcol] = acc[jj] * As[r][66];
    }
}

// ---------------- Kernel 3: attn rescale (bh 0..14) ----------------
__global__ __launch_bounds__(256) void rescale_kernel(
    float* __restrict__ attn, const float* __restrict__ cfg)
{
    size_t tid = (size_t)blockIdx.x * 256 + threadIdx.x;
    size_t e4  = tid * 4;                  // < 15*LL2
    int bh  = (int)(e4 >> 22);
    int rem = (int)(e4 & (LL2 - 1));
    int qg  = rem >> 11;
    int k   = rem & (LL - 1);
    float cf = cfg[((size_t)(bh * LL + qg)) * 32 + (k >> 6)];
    float4* p = (float4*)(attn + e4);
    float4 v = *p;
    v.x *= cf; v.y *= cf; v.z *= cf; v.w *= cf;
    *p = v;
}

// ---------------- Kernel 4: output projection ----------------
__global__ __launch_bounds__(256) void out_gemm_kernel(
    const float* __restrict__ ctx, const float* __restrict__ Wo, float* __restrict__ Y)
{
    __shared__ float Xs[64][33];
    __shared__ float Ws[64][33];

    const int t  = threadIdx.x;
    const int m0 = blockIdx.x * 64;
    const int n0 = blockIdx.y * 64;
    const int ty = t >> 4;
    const int tx = t & 15;

    float acc[4][4] = {};

    for (int kt = 0; kt < 8; ++kt) {
#pragma unroll
        for (int r = 0; r < 2; ++r) {
            int f   = t + 256*r;
            int row = f >> 3;
            int c   = (f & 7) << 2;
            int grow = m0 + row;
            int b = grow / LL, l = grow % LL;
            float4 xv4 = *(const float4*)(ctx + (size_t)((b*NH + kt)*LL + l) * DHEAD + c);
            Xs[row][c+0]=xv4.x; Xs[row][c+1]=xv4.y; Xs[row][c+2]=xv4.z; Xs[row][c+3]=xv4.w;
            float4 wv4 = *(const float4*)(Wo + (size_t)(n0 + row) * DMODEL + kt*32 + c);
            Ws[row][c+0]=wv4.x; Ws[row][c+1]=wv4.y; Ws[row][c+2]=wv4.z; Ws[row][c+3]=wv4.w;
        }
        __syncthreads();
#pragma unroll
        for (int kk = 0; kk < 32; ++kk) {
            float a[4], bv[4];
#pragma unroll
            for (int i = 0; i < 4; ++i) a[i]  = Xs[ty*4+i][kk];
#pragma unroll
            for (int j = 0; j < 4; ++j) bv[j] = Ws[tx*4+j][kk];
#pragma unroll
            for (int i = 0; i < 4; ++i)
#pragma unroll
                for (int j = 0; j < 4; ++j)
                    acc[i][j] = fmaf(a[i], bv[j], acc[i][j]);
        }
        __syncthreads();
    }

#pragma unroll
    for (int i = 0; i < 4; ++i) {
        int row = m0 + ty*4 + i;
#pragma unroll
        for (int j = 0; j < 4; ++j) {
            int col = n0 + tx*4 + j;
            Y[(size_t)row * DMODEL + col] = acc[i][j];
        }
    }
}

// ---------------- Kernel 5: attn writes for bh==15 ----------------
__global__ __launch_bounds__(256) void attn15_kernel(
    const float* __restrict__ Q15, const float* __restrict__ K15,
    const int* __restrict__ mask, const float* __restrict__ adj, const float* __restrict__ dist,
    const float* __restrict__ wA, const float* __restrict__ wD,
    const float* __restrict__ Mw, const float* __restrict__ Sw,
    float* __restrict__ attn15)
{
    const int t    = threadIdx.x;
    const int q0   = blockIdx.x * 32;
    const int kcol = t & 63;
    const int wid  = t >> 6;

    __shared__ float Qs[32][36];
    __shared__ float Ks[128][36];

    const float wa = wA[7];
    const float wd = wD[7];

    {
        int row = t >> 3;
        int c   = (t & 7) << 2;
        float4 qv = *(const float4*)(Q15 + (size_t)(q0 + row) * DHEAD + c);
        Qs[row][c+0] = qv.x; Qs[row][c+1] = qv.y; Qs[row][c+2] = qv.z; Qs[row][c+3] = qv.w;
    }

    float Mr[8], Sr[8];
#pragma unroll
    for (int j = 0; j < 8; ++j) {
        int qg = q0 + wid + 4*j;
        Mr[j] = Mw[qg];
        Sr[j] = Sw[qg];
    }

    for (int kt = 0; kt < 16; ++kt) {
#pragma unroll
        for (int r = 0; r < 4; ++r) {
            int f   = t + 256 * r;
            int row = f >> 3;
            int c   = (f & 7) << 2;
            float4 kv = *(const float4*)(K15 + (size_t)(kt*128 + row) * DHEAD + c);
            Ks[row][c+0]=kv.x; Ks[row][c+1]=kv.y; Ks[row][c+2]=kv.z; Ks[row][c+3]=kv.w;
        }
        __syncthreads();

        float4 k0[8], k1[8];
        {
            const float4* p0 = (const float4*)&Ks[kcol][0];
            const float4* p1 = (const float4*)&Ks[kcol + 64][0];
#pragma unroll
            for (int c = 0; c < 8; ++c) { k0[c] = p0[c]; k1[c] = p1[c]; }
        }

        const int kg0 = kt*128 + kcol;
#pragma unroll
        for (int j = 0; j < 8; ++j) {
            int qq = wid + 4*j;
            float s0 = 0.f, s1 = 0.f;
            const float4* qp = (const float4*)&Qs[qq][0];
#pragma unroll
            for (int c = 0; c < 8; ++c) {
                float4 q4 = qp[c];
                s0 += q4.x*k0[c].x + q4.y*k0[c].y + q4.z*k0[c].z + q4.w*k0[c].w;
                s1 += q4.x*k1[c].x + q4.y*k1[c].y + q4.z*k1[c].z + q4.w*k1[c].w;
            }
            int qg = q0 + qq;
            size_t mi0 = (size_t)(LL + qg) * LL + kg0;      // b = 1
            size_t mi1 = mi0 + 64;
            float sm0 = (mask[mi0] == 1) ? s0 : 0.0f;
            float sm1 = (mask[mi1] == 1) ? s1 : 0.0f;
            float l0 = sm0 * (1.0f + adj[mi0]*wa + dist[mi0]*wd) * SCALE_INV;
            float l1 = sm1 * (1.0f + adj[mi1]*wa + dist[mi1]*wd) * SCALE_INV;
            size_t ai = (size_t)qg * LL + kg0;
            attn15[ai]      = __expf(l0 - Mr[j]) * Sr[j];
            attn15[ai + 64] = __expf(l1 - Mr[j]) * Sr[j];
        }
        __syncthreads();
    }
}

extern "C" void kernel_launch(void* const* d_in, const int* in_sizes, int n_in,
                              void* d_out, int out_size, void* d_ws, size_t ws_size,
                              hipStream_t stream)
{
    const float* q    = (const float*)d_in[0];
    const float* k    = (const float*)d_in[1];
    const float* v    = (const float*)d_in[2];
    const int*   mask = (const int*)d_in[3];
    const float* adj  = (const float*)d_in[4];
    const float* dist = (const float*)d_in[5];
    const float* Wq   = (const float*)d_in[6];
    const float* Wk   = (const float*)d_in[7];
    const float* Wv   = (const float*)d_in[8];
    const float* Wo   = (const float*)d_in[9];
    const float* wA   = (const float*)d_in[10];
    const float* wD   = (const float*)d_in[11];

    float* out  = (float*)d_out;                       // B*L*DM = 1,048,576 floats
    float* attn = out + (size_t)BB*LL*DMODEL;          // B*H*L*L

    // Scratch parked in attn[bh=15]'s slab (4*NQ floats = 16 MB, dead until attn15).
    float* tail = attn + (size_t)15 * LL2;
    float* Qw = tail;
    float* Kw = tail + (size_t)NQ;
    float* Vw = tail + (size_t)2 * NQ;
    float* Cw = tail + (size_t)3 * NQ;

    // cf parked in `out` (exactly 16*2048*32 = 1,048,576 floats; dead until out_gemm).
    float* cfg = out;

    // Tiny ws: bh=15 Q/K slices + final softmax stats (528 KB).
    float* Q15 = (float*)d_ws;
    float* K15 = Q15 + (size_t)LL * DHEAD;
    float* Mw  = K15 + (size_t)LL * DHEAD;
    float* Sw  = Mw + LL;

    dim3 g1(64, 4, 3);
    proj_kernel<<<g1, 256, 0, stream>>>(q, k, v, Wq, Wk, Wv, Qw, Kw, Vw, Q15, K15);

    dim3 g2(LL/32, BB*NH);
    attn_main_kernel<<<g2, 256, 0, stream>>>(Qw, Kw, Vw, mask, adj, dist, wA, wD,
                                             attn, Cw, cfg, Mw, Sw);

    rescale_kernel<<<15 * LL2 / 4 / 256, 256, 0, stream>>>(attn, cfg);

    dim3 g3(64, 4);
    out_gemm_kernel<<<g3, 256, 0, stream>>>(Cw, Wo, out);

    attn15_kernel<<<LL/32, 256, 0, stream>>>(Q15, K15, mask, adj, dist, wA, wD, Mw, Sw,
                                             attn + (size_t)15 * LL2);
}

// Round 4
// 1315.702 us; speedup vs baseline: 1.3586x; 1.2926x over previous
//
#include <hip/hip_runtime.h>
#include <math.h>

#define BB 2
#define LL 2048
#define DMODEL 256
#define NH 8
#define DHEAD 32
#define LL2 (LL*LL)            // 4,194,304 floats per (b,h) attn slab
#define NQ (BB*NH*LL*DHEAD)    // 1,048,576 floats per Q/K/V/ctx tensor

constexpr float SCALE_INV = 0.17677669529663687f;  // 1/sqrt(32)

// ---------------- Kernel 1: QKV projections ----------------
__global__ __launch_bounds__(256) void proj_kernel(
    const float* __restrict__ xq, const float* __restrict__ xk, const float* __restrict__ xv,
    const float* __restrict__ Wq, const float* __restrict__ Wk, const float* __restrict__ Wv,
    float* __restrict__ Qo, float* __restrict__ Ko, float* __restrict__ Vo,
    float* __restrict__ Q15, float* __restrict__ K15)
{
    const float* X; const float* W; float* O; float* dup;
    if (blockIdx.z == 0)      { X = xq; W = Wq; O = Qo; dup = Q15; }
    else if (blockIdx.z == 1) { X = xk; W = Wk; O = Ko; dup = K15; }
    else                      { X = xv; W = Wv; O = Vo; dup = nullptr; }

    __shared__ float Xs[64][33];
    __shared__ float Ws[64][33];

    const int t  = threadIdx.x;
    const int m0 = blockIdx.x * 64;
    const int n0 = blockIdx.y * 64;
    const int ty = t >> 4;
    const int tx = t & 15;

    float acc[4][4] = {};

    for (int k0 = 0; k0 < DMODEL; k0 += 32) {
#pragma unroll
        for (int r = 0; r < 2; ++r) {
            int f   = t + 256 * r;
            int row = f >> 3;
            int c   = (f & 7) << 2;
            float4 xv4 = *(const float4*)(X + (size_t)(m0 + row) * DMODEL + k0 + c);
            Xs[row][c+0] = xv4.x; Xs[row][c+1] = xv4.y; Xs[row][c+2] = xv4.z; Xs[row][c+3] = xv4.w;
            float4 wv4 = *(const float4*)(W + (size_t)(n0 + row) * DMODEL + k0 + c);
            Ws[row][c+0] = wv4.x; Ws[row][c+1] = wv4.y; Ws[row][c+2] = wv4.z; Ws[row][c+3] = wv4.w;
        }
        __syncthreads();
#pragma unroll
        for (int kk = 0; kk < 32; ++kk) {
            float a[4], bv[4];
#pragma unroll
            for (int i = 0; i < 4; ++i) a[i]  = Xs[ty*4+i][kk];
#pragma unroll
            for (int j = 0; j < 4; ++j) bv[j] = Ws[tx*4+j][kk];
#pragma unroll
            for (int i = 0; i < 4; ++i)
#pragma unroll
                for (int j = 0; j < 4; ++j)
                    acc[i][j] = fmaf(a[i], bv[j], acc[i][j]);
        }
        __syncthreads();
    }

#pragma unroll
    for (int i = 0; i < 4; ++i) {
        int row = m0 + ty*4 + i;
        int b   = row / LL;
        int l   = row % LL;
#pragma unroll
        for (int j = 0; j < 4; ++j) {
            int col = n0 + tx*4 + j;
            int h   = col >> 5;
            int d   = col & 31;
            O[(size_t)(((b*NH + h)*LL) + l) * DHEAD + d] = acc[i][j];
            if (dup && row >= LL && col >= 224) {
                dup[(size_t)(row - LL) * DHEAD + (col - 224)] = acc[i][j];
            }
        }
    }
}

// ---------------- Kernel 2: single-pass flash, raw-logit attn store ----------------
// One block per (b,h, 32-row q tile); 32 k-tiles of 64.
// attn (bh<15) receives RAW logits l; rescale_kernel later applies exp(l-M)*invS.
// Per-lane partial softmax sums (no per-tile sum butterfly); only the max
// butterfly remains in the k-loop. mask/adj/dist prefetched one tile ahead.
__global__ __launch_bounds__(256, 4) void attn_main_kernel(
    const float* __restrict__ Q, const float* __restrict__ K, const float* __restrict__ V,
    const int* __restrict__ mask, const float* __restrict__ adj, const float* __restrict__ dist,
    const float* __restrict__ wA, const float* __restrict__ wD,
    float* __restrict__ attn, float* __restrict__ ctx,
    float* __restrict__ Mall, float* __restrict__ Sall,
    float* __restrict__ Mw, float* __restrict__ Sw)
{
    const int t    = threadIdx.x;
    const int bh   = blockIdx.y;
    const int b    = bh >> 3;
    const int h    = bh & 7;
    const int q0   = blockIdx.x * 32;
    const int kcol = t & 63;
    const int wid  = t >> 6;
    const int dcol = t & 31;
    const int grp  = t >> 5;

    __shared__ float Qs[32][36];
    __shared__ float Ks[64][36];
    __shared__ float Vs[64][36];
    __shared__ float As[32][68];   // 0..63 = p; 64 = alpha; 65 = invS

    const float wa = wA[h];
    const float wd = wD[h];

    {   // Q tile 32x32
        int row = t >> 3;
        int c   = (t & 7) << 2;
        float4 qv = *(const float4*)(Q + (size_t)(bh * LL + q0 + row) * DHEAD + c);
        Qs[row][c+0] = qv.x; Qs[row][c+1] = qv.y; Qs[row][c+2] = qv.z; Qs[row][c+3] = qv.w;
    }

    float m[8], s[8];
#pragma unroll
    for (int j = 0; j < 8; ++j) { m[j] = -INFINITY; s[j] = 0.0f; }
    float acc[4] = {0.f, 0.f, 0.f, 0.f};

    const size_t kv_base = (size_t)bh * LL * DHEAD;
    const size_t mrow    = (size_t)(b * LL + q0);   // base row in mask-class tensors

    // prefetch tile 0's mask/adj/dist (8 rows per lane)
    int   msk[8]; float av[8], dv[8];
#pragma unroll
    for (int j = 0; j < 8; ++j) {
        size_t mi = (mrow + wid + 4*j) * LL + kcol;
        msk[j] = mask[mi]; av[j] = adj[mi]; dv[j] = dist[mi];
    }

    for (int kt = 0; kt < 32; ++kt) {
        // stage K,V tile (64 x 32)
#pragma unroll
        for (int r = 0; r < 2; ++r) {
            int f   = t + 256 * r;
            int row = f >> 3;
            int c   = (f & 7) << 2;
            float4 kv = *(const float4*)(K + kv_base + (size_t)(kt*64 + row) * DHEAD + c);
            Ks[row][c+0]=kv.x; Ks[row][c+1]=kv.y; Ks[row][c+2]=kv.z; Ks[row][c+3]=kv.w;
            float4 vv = *(const float4*)(V + kv_base + (size_t)(kt*64 + row) * DHEAD + c);
            Vs[row][c+0]=vv.x; Vs[row][c+1]=vv.y; Vs[row][c+2]=vv.z; Vs[row][c+3]=vv.w;
        }
        __syncthreads();

        float4 kf[8];
        {
            const float4* kp = (const float4*)&Ks[kcol][0];
#pragma unroll
            for (int c = 0; c < 8; ++c) kf[c] = kp[c];
        }

        const int kg = kt*64 + kcol;
        float lv[8];
#pragma unroll
        for (int j = 0; j < 8; ++j) {
            int qq = wid + 4*j;
            float s0 = 0.f;
            const float4* qp = (const float4*)&Qs[qq][0];
#pragma unroll
            for (int c = 0; c < 8; ++c) {
                float4 q4 = qp[c];
                s0 += q4.x*kf[c].x + q4.y*kf[c].y + q4.z*kf[c].z + q4.w*kf[c].w;
            }
            float sm = (msk[j] == 1) ? s0 : 0.0f;
            lv[j] = sm * (1.0f + av[j]*wa + dv[j]*wd) * SCALE_INV;
            if (bh != 15) attn[(size_t)(bh * LL + q0 + qq) * LL + kg] = lv[j];
        }

        // 8 independent max butterflies
        float mloc[8];
#pragma unroll
        for (int j = 0; j < 8; ++j) mloc[j] = lv[j];
#pragma unroll
        for (int off = 1; off < 64; off <<= 1)
#pragma unroll
            for (int j = 0; j < 8; ++j)
                mloc[j] = fmaxf(mloc[j], __shfl_xor(mloc[j], off, 64));

#pragma unroll
        for (int j = 0; j < 8; ++j) {
            int qq = wid + 4*j;
            float mnew  = fmaxf(m[j], mloc[j]);
            float alpha = __expf(m[j] - mnew);
            float p     = __expf(lv[j] - mnew);
            s[j] = s[j]*alpha + p;         // per-lane partial sum
            m[j] = mnew;
            As[qq][kcol] = p;
            if (kcol == 0) As[qq][64] = alpha;
        }
        __syncthreads();

        // prefetch next tile's mask/adj/dist while PV runs
        if (kt + 1 < 32) {
            const int kgn = (kt+1)*64 + kcol;
#pragma unroll
            for (int j = 0; j < 8; ++j) {
                size_t mi = (mrow + wid + 4*j) * LL + kgn;
                msk[j] = mask[mi]; av[j] = adj[mi]; dv[j] = dist[mi];
            }
        }

        // PV: thread (grp,dcol) accumulates rows grp*4..+3, d = dcol
        float sum[4] = {0.f, 0.f, 0.f, 0.f};
#pragma unroll
        for (int c = 0; c < 16; ++c) {
            int kl = c * 4;
            float v0 = Vs[kl+0][dcol];
            float v1 = Vs[kl+1][dcol];
            float v2 = Vs[kl+2][dcol];
            float v3 = Vs[kl+3][dcol];
#pragma unroll
            for (int jj = 0; jj < 4; ++jj) {
                float4 a4 = *(const float4*)&As[grp*4+jj][kl];
                sum[jj] += a4.x*v0 + a4.y*v1 + a4.z*v2 + a4.w*v3;
            }
        }
#pragma unroll
        for (int jj = 0; jj < 4; ++jj) {
            int r = grp*4 + jj;
            acc[jj] = acc[jj]*As[r][64] + sum[jj];
        }
        __syncthreads();
    }

    // epilogue: one sum butterfly per row; stats out; ctx scale
#pragma unroll
    for (int j = 0; j < 8; ++j) {
        float ss = s[j];
#pragma unroll
        for (int off = 1; off < 64; off <<= 1)
            ss += __shfl_xor(ss, off, 64);
        float inv = 1.0f / ss;
        int qq = wid + 4*j;
        int qg = q0 + qq;
        if (kcol == 0) {
            As[qq][65] = inv;
            if (bh != 15) { Mall[bh*LL + qg] = m[j]; Sall[bh*LL + qg] = inv; }
            else          { Mw[qg] = m[j];           Sw[qg] = inv; }
        }
    }
    __syncthreads();

#pragma unroll
    for (int jj = 0; jj < 4; ++jj) {
        int r  = grp*4 + jj;
        int qg = q0 + r;
        ctx[(size_t)(bh * LL + qg) * DHEAD + dcol] = acc[jj] * As[r][65];
    }
}

// ---------------- Kernel 3: attn finalize (bh 0..14): p = exp(l-M)*invS ----------------
__global__ __launch_bounds__(256) void rescale_kernel(
    float* __restrict__ attn, const float* __restrict__ Mall, const float* __restrict__ Sall)
{
    size_t tid = (size_t)blockIdx.x * 256 + threadIdx.x;
    size_t e4  = tid * 4;                  // < 15*LL2
    int bh  = (int)(e4 >> 22);
    int row = (int)((e4 >> 11) & (LL - 1));
    float Mv = Mall[bh*LL + row];
    float Sv = Sall[bh*LL + row];
    float4* p = (float4*)(attn + e4);
    float4 v = *p;
    v.x = __expf(v.x - Mv) * Sv;
    v.y = __expf(v.y - Mv) * Sv;
    v.z = __expf(v.z - Mv) * Sv;
    v.w = __expf(v.w - Mv) * Sv;
    *p = v;
}

// ---------------- Kernel 4: output projection ----------------
__global__ __launch_bounds__(256) void out_gemm_kernel(
    const float* __restrict__ ctx, const float* __restrict__ Wo, float* __restrict__ Y)
{
    __shared__ float Xs[64][33];
    __shared__ float Ws[64][33];

    const int t  = threadIdx.x;
    const int m0 = blockIdx.x * 64;
    const int n0 = blockIdx.y * 64;
    const int ty = t >> 4;
    const int tx = t & 15;

    float acc[4][4] = {};

    for (int kt = 0; kt < 8; ++kt) {
#pragma unroll
        for (int r = 0; r < 2; ++r) {
            int f   = t + 256*r;
            int row = f >> 3;
            int c   = (f & 7) << 2;
            int grow = m0 + row;
            int b = grow / LL, l = grow % LL;
            float4 xv4 = *(const float4*)(ctx + (size_t)((b*NH + kt)*LL + l) * DHEAD + c);
            Xs[row][c+0]=xv4.x; Xs[row][c+1]=xv4.y; Xs[row][c+2]=xv4.z; Xs[row][c+3]=xv4.w;
            float4 wv4 = *(const float4*)(Wo + (size_t)(n0 + row) * DMODEL + kt*32 + c);
            Ws[row][c+0]=wv4.x; Ws[row][c+1]=wv4.y; Ws[row][c+2]=wv4.z; Ws[row][c+3]=wv4.w;
        }
        __syncthreads();
#pragma unroll
        for (int kk = 0; kk < 32; ++kk) {
            float a[4], bv[4];
#pragma unroll
            for (int i = 0; i < 4; ++i) a[i]  = Xs[ty*4+i][kk];
#pragma unroll
            for (int j = 0; j < 4; ++j) bv[j] = Ws[tx*4+j][kk];
#pragma unroll
            for (int i = 0; i < 4; ++i)
#pragma unroll
                for (int j = 0; j < 4; ++j)
                    acc[i][j] = fmaf(a[i], bv[j], acc[i][j]);
        }
        __syncthreads();
    }

#pragma unroll
    for (int i = 0; i < 4; ++i) {
        int row = m0 + ty*4 + i;
#pragma unroll
        for (int j = 0; j < 4; ++j) {
            int col = n0 + tx*4 + j;
            Y[(size_t)row * DMODEL + col] = acc[i][j];
        }
    }
}

// ---------------- Kernel 5: attn writes for bh==15, split-k ----------------
// grid (64, 8): q-tile x, k-range y (2 tiles of 128 each).
__global__ __launch_bounds__(256) void attn15_kernel(
    const float* __restrict__ Q15, const float* __restrict__ K15,
    const int* __restrict__ mask, const float* __restrict__ adj, const float* __restrict__ dist,
    const float* __restrict__ wA, const float* __restrict__ wD,
    const float* __restrict__ Mw, const float* __restrict__ Sw,
    float* __restrict__ attn15)
{
    const int t    = threadIdx.x;
    const int q0   = blockIdx.x * 32;
    const int kt0  = blockIdx.y * 2;
    const int kcol = t & 63;
    const int wid  = t >> 6;

    __shared__ float Qs[32][36];
    __shared__ float Ks[128][36];

    const float wa = wA[7];
    const float wd = wD[7];

    {
        int row = t >> 3;
        int c   = (t & 7) << 2;
        float4 qv = *(const float4*)(Q15 + (size_t)(q0 + row) * DHEAD + c);
        Qs[row][c+0] = qv.x; Qs[row][c+1] = qv.y; Qs[row][c+2] = qv.z; Qs[row][c+3] = qv.w;
    }

    float Mr[8], Sr[8];
#pragma unroll
    for (int j = 0; j < 8; ++j) {
        int qg = q0 + wid + 4*j;
        Mr[j] = Mw[qg];
        Sr[j] = Sw[qg];
    }

    for (int kt = kt0; kt < kt0 + 2; ++kt) {
#pragma unroll
        for (int r = 0; r < 4; ++r) {
            int f   = t + 256 * r;
            int row = f >> 3;
            int c   = (f & 7) << 2;
            float4 kv = *(const float4*)(K15 + (size_t)(kt*128 + row) * DHEAD + c);
            Ks[row][c+0]=kv.x; Ks[row][c+1]=kv.y; Ks[row][c+2]=kv.z; Ks[row][c+3]=kv.w;
        }
        __syncthreads();

        float4 k0[8], k1[8];
        {
            const float4* p0 = (const float4*)&Ks[kcol][0];
            const float4* p1 = (const float4*)&Ks[kcol + 64][0];
#pragma unroll
            for (int c = 0; c < 8; ++c) { k0[c] = p0[c]; k1[c] = p1[c]; }
        }

        const int kg0 = kt*128 + kcol;
#pragma unroll
        for (int j = 0; j < 8; ++j) {
            int qq = wid + 4*j;
            float s0 = 0.f, s1 = 0.f;
            const float4* qp = (const float4*)&Qs[qq][0];
#pragma unroll
            for (int c = 0; c < 8; ++c) {
                float4 q4 = qp[c];
                s0 += q4.x*k0[c].x + q4.y*k0[c].y + q4.z*k0[c].z + q4.w*k0[c].w;
                s1 += q4.x*k1[c].x + q4.y*k1[c].y + q4.z*k1[c].z + q4.w*k1[c].w;
            }
            int qg = q0 + qq;
            size_t mi0 = (size_t)(LL + qg) * LL + kg0;      // b = 1
            size_t mi1 = mi0 + 64;
            float sm0 = (mask[mi0] == 1) ? s0 : 0.0f;
            float sm1 = (mask[mi1] == 1) ? s1 : 0.0f;
            float l0 = sm0 * (1.0f + adj[mi0]*wa + dist[mi0]*wd) * SCALE_INV;
            float l1 = sm1 * (1.0f + adj[mi1]*wa + dist[mi1]*wd) * SCALE_INV;
            size_t ai = (size_t)qg * LL + kg0;
            attn15[ai]      = __expf(l0 - Mr[j]) * Sr[j];
            attn15[ai + 64] = __expf(l1 - Mr[j]) * Sr[j];
        }
        __syncthreads();
    }
}

extern "C" void kernel_launch(void* const* d_in, const int* in_sizes, int n_in,
                              void* d_out, int out_size, void* d_ws, size_t ws_size,
                              hipStream_t stream)
{
    const float* q    = (const float*)d_in[0];
    const float* k    = (const float*)d_in[1];
    const float* v    = (const float*)d_in[2];
    const int*   mask = (const int*)d_in[3];
    const float* adj  = (const float*)d_in[4];
    const float* dist = (const float*)d_in[5];
    const float* Wq   = (const float*)d_in[6];
    const float* Wk   = (const float*)d_in[7];
    const float* Wv   = (const float*)d_in[8];
    const float* Wo   = (const float*)d_in[9];
    const float* wA   = (const float*)d_in[10];
    const float* wD   = (const float*)d_in[11];

    float* out  = (float*)d_out;                       // B*L*DM = 1,048,576 floats
    float* attn = out + (size_t)BB*LL*DMODEL;          // B*H*L*L

    // Scratch parked in attn[bh=15]'s slab (4*NQ floats = 16 MB, dead until attn15).
    float* tail = attn + (size_t)15 * LL2;
    float* Qw = tail;
    float* Kw = tail + (size_t)NQ;
    float* Vw = tail + (size_t)2 * NQ;
    float* Cw = tail + (size_t)3 * NQ;

    // Final softmax stats (bh<15) parked in `out` (dead until out_gemm).
    float* Mall = out;                 // 15*2048 floats
    float* Sall = out + 32768;         // 15*2048 floats

    // Tiny ws: bh=15 Q/K slices + bh=15 stats (528 KB).
    float* Q15 = (float*)d_ws;
    float* K15 = Q15 + (size_t)LL * DHEAD;
    float* Mw  = K15 + (size_t)LL * DHEAD;
    float* Sw  = Mw + LL;

    dim3 g1(64, 4, 3);
    proj_kernel<<<g1, 256, 0, stream>>>(q, k, v, Wq, Wk, Wv, Qw, Kw, Vw, Q15, K15);

    dim3 g2(LL/32, BB*NH);
    attn_main_kernel<<<g2, 256, 0, stream>>>(Qw, Kw, Vw, mask, adj, dist, wA, wD,
                                             attn, Cw, Mall, Sall, Mw, Sw);

    rescale_kernel<<<15 * LL2 / 4 / 256, 256, 0, stream>>>(attn, Mall, Sall);

    dim3 g3(64, 4);
    out_gemm_kernel<<<g3, 256, 0, stream>>>(Cw, Wo, out);

    dim3 g4(64, 8);
    attn15_kernel<<<g4, 256, 0, stream>>>(Q15, K15, mask, adj, dist, wA, wD, Mw, Sw,
                                          attn + (size_t)15 * LL2);
}